// Round 11
// baseline (425.402 us; speedup 1.0000x reference)
//
#include <hip/hip_runtime.h>
#include <hip/hip_bf16.h>

// AttentiveGraph: B=4, N=10000, E=160000, C=F=128, 3 iterations.
// R11: (a) edge_dst u16 (node ids < 10000) — halves index traffic in edge
// kernel + csr_fill. (b) edge gather loop 16-deep (was 8): R10 VGPR=20 shows
// huge headroom; discriminates latency-bound vs fabric-bw-bound. (c) fused
// mid/final stage the 32x128 lgsa tile in LDS once (uint4 coalesced, pad 132)
// — kills the second scalar global read pass for sa. R10 structure otherwise.

#define BATCH 4
#define NNODE 10000
#define NEDGE 160000
#define TWOE  (2*NEDGE)
#define MROWS (BATCH*NNODE)   // 40000
#define NCHUNK 64
#define CHUNKE (NEDGE/NCHUNK) // 2500
#define PADN  10240

typedef unsigned short u16;
typedef unsigned int   u32;
typedef __attribute__((ext_vector_type(8))) short bf16x8_t;
typedef __attribute__((ext_vector_type(4))) float f32x4_t;

__device__ __forceinline__ float b2f(u16 h){ return __uint_as_float(((u32)h) << 16); }
__device__ __forceinline__ u16 f2bf(float f){
  u32 u = __float_as_uint(f);
  return (u16)((u + 0x7fffu + ((u >> 16) & 1u)) >> 16);   // RNE
}
__device__ __forceinline__ float fast_tanh(float x){
  float e = __expf(2.0f * x);
  return fmaf(-2.0f, __builtin_amdgcn_rcpf(e + 1.0f), 1.0f);
}

// ---------------- storage dtype probe (fp32 vs bf16 storage) ------------------
__global__ void detect_dtype(const u32* __restrict__ objw, int* __restrict__ flag){
  __shared__ int zc, hc;
  if (threadIdx.x == 0){ zc = 0; hc = 0; }
  __syncthreads();
  int z = 0, h = 0;
  for (int i = threadIdx.x; i < 1024; i += 256){
    u32 lo = objw[i] & 0xffffu;
    if (lo == 0) z++;
    if (((lo >> 7) & 0xffu) >= 160u) h++;
  }
  atomicAdd(&zc, z); atomicAdd(&hc, h);
  __syncthreads();
  if (threadIdx.x == 0) *flag = (hc > 0 || zc > 512) ? 1 : 0;   // 1 = fp32 storage
}

// Wt[m][c*128+k] = W_m[k*128+c]; tail block converts biases.
__global__ void prep_weights(const void* __restrict__ Wo, const void* __restrict__ Wa,
                             const void* __restrict__ Wla, const void* __restrict__ Wl,
                             const void* __restrict__ ab, const void* __restrict__ sb,
                             const int* __restrict__ flag, u16* __restrict__ Wt,
                             float* __restrict__ biasf){
  int idx = blockIdx.x * 256 + threadIdx.x;
  bool f = (*flag != 0);
  if (idx < 65536){
    int m = idx >> 14, k = (idx >> 7) & 127, c = idx & 127;
    const void* src = (m == 0) ? Wo : (m == 1) ? Wa : (m == 2) ? Wla : Wl;
    u16 h = f ? f2bf(((const float*)src)[k * 128 + c]) : ((const u16*)src)[k * 128 + c];
    Wt[m * 16384 + c * 128 + k] = h;
  } else {
    int t = idx - 65536;
    const void* src = (t < 128) ? sb : ab;
    int i = t & 127;
    biasf[t] = f ? ((const float*)src)[i] : b2f(((const u16*)src)[i]);
  }
}

// ---------------- CSR build: 3-phase chunked histogram ------------------------
__device__ __forceinline__ void chunk_of(int blk, int& b, int& c){
  int xcd = blk & 7;
  b = xcd >> 1;
  c = ((blk >> 3) << 1) | (xcd & 1);           // 0..63
}

__global__ void __launch_bounds__(256) csr_hist(const int* __restrict__ conn,
                                                u16* __restrict__ partial){
  int b, c; chunk_of(blockIdx.x, b, c);
  __shared__ u32 hist[NNODE];
  for (int n = threadIdx.x; n < NNODE; n += 256) hist[n] = 0;
  __syncthreads();
  const int2* cp = (const int2*)conn + (size_t)b * NEDGE + c * CHUNKE;
  for (int i = threadIdx.x; i < CHUNKE; i += 256){
    int2 e = cp[i];
    atomicAdd(&hist[e.x], 1);
    atomicAdd(&hist[e.y], 1);
  }
  __syncthreads();
  u16* prow = partial + (size_t)(b * NCHUNK + c) * PADN;
  for (int n = threadIdx.x; n < NNODE; n += 256) prow[n] = (u16)hist[n];
}

__global__ void __launch_bounds__(256) csr_colscan(u16* __restrict__ partial,
    int* __restrict__ row_start, int* __restrict__ bsum){
  int b = blockIdx.x / 40, w = blockIdx.x % 40;
  int n = w * 256 + threadIdx.x;
  u32 run = 0;
  if (n < NNODE){
    #pragma unroll 8
    for (int c = 0; c < NCHUNK; c++){
      size_t idx = (size_t)(b * NCHUNK + c) * PADN + n;
      u32 v = partial[idx];
      partial[idx] = (u16)run;
      run += v;
    }
  }
  __shared__ u32 buf[256];
  buf[threadIdx.x] = run;
  __syncthreads();
  for (int off = 1; off < 256; off <<= 1){
    u32 x = (threadIdx.x >= (unsigned)off) ? buf[threadIdx.x - off] : 0;
    __syncthreads();
    buf[threadIdx.x] += x;
    __syncthreads();
  }
  u32 incl = buf[threadIdx.x];
  if (n < NNODE) row_start[b * (NNODE + 1) + n] = (int)(incl - run);  // window-local
  if (threadIdx.x == 255) bsum[blockIdx.x] = (int)incl;
}

__global__ void scanB(const int* __restrict__ bsum, int* __restrict__ boff,
                      int* __restrict__ row_start){
  __shared__ int s[160];
  if (threadIdx.x < 160) s[threadIdx.x] = bsum[threadIdx.x];
  __syncthreads();
  if (threadIdx.x < 160){
    int b = threadIdx.x / 40, j = threadIdx.x % 40;
    int off = 0;
    for (int q = b * 40; q < b * 40 + j; q++) off += s[q];
    boff[threadIdx.x] = off;
  }
  if (threadIdx.x < BATCH) row_start[threadIdx.x * (NNODE + 1) + NNODE] = TWOE;
}

__global__ void scanC(int* __restrict__ row_start, const int* __restrict__ boff){
  int b = blockIdx.x / 40, j = blockIdx.x % 40;
  int n = j * 256 + threadIdx.x;
  if (n < NNODE) row_start[b * (NNODE + 1) + n] += boff[blockIdx.x];
}

__global__ void __launch_bounds__(256) csr_fill(const int* __restrict__ conn,
    const u16* __restrict__ partial, const int* __restrict__ row_start,
    u16* __restrict__ edge_dst){
  int b, c; chunk_of(blockIdx.x, b, c);
  __shared__ u32 cur[NNODE];
  const u16* prow = partial + (size_t)(b * NCHUNK + c) * PADN;
  const int* rs = row_start + b * (NNODE + 1);
  for (int n = threadIdx.x; n < NNODE; n += 256) cur[n] = (u32)rs[n] + prow[n];
  __syncthreads();
  const int2* cp = (const int2*)conn + (size_t)b * NEDGE + c * CHUNKE;
  u16* edb = edge_dst + (size_t)b * TWOE;
  for (int i = threadIdx.x; i < CHUNKE; i += 256){
    int2 e = cp[i];
    u32 p1 = atomicAdd(&cur[e.x], 1); edb[p1] = (u16)e.y;
    u32 p2 = atomicAdd(&cur[e.y], 1); edb[p2] = (u16)e.x;
  }
}

// ---------------- MFMA helpers (wave = 16 rows x 64 cols) ---------------------
__device__ __forceinline__ void gemm_tile4(const u16* __restrict__ arow,
    const u16* __restrict__ wt, int lm, int lq, int cofs, f32x4_t acc[4]){
  #pragma unroll
  for (int ks = 0; ks < 4; ks++){
    bf16x8_t a = *(const bf16x8_t*)(arow + ks * 32);
    #pragma unroll
    for (int nb = 0; nb < 4; nb++){
      bf16x8_t bfr = *(const bf16x8_t*)(wt + (cofs + nb * 16 + lm) * 128 + ks * 32 + lq * 8);
      acc[nb] = __builtin_amdgcn_mfma_f32_16x16x32_bf16(a, bfr, acc[nb], 0, 0, 0);
    }
  }
}

// A-frag from LDS-staged lgsa tile (pad 132 u32/row). lgrow = &lgt[lr*132].
__device__ __forceinline__ void gemm_tile4_lds(const u32* __restrict__ lgrow,
    const u16* __restrict__ wt, int lm, int lq, int cofs, f32x4_t acc[4]){
  #pragma unroll
  for (int ks = 0; ks < 4; ks++){
    uint4 wa = *(const uint4*)(lgrow + ks * 32 + lq * 8);
    uint4 wb = *(const uint4*)(lgrow + ks * 32 + lq * 8 + 4);
    bf16x8_t a;
    a[0] = (short)wa.x; a[1] = (short)wa.y; a[2] = (short)wa.z; a[3] = (short)wa.w;
    a[4] = (short)wb.x; a[5] = (short)wb.y; a[6] = (short)wb.z; a[7] = (short)wb.w;
    #pragma unroll
    for (int nb = 0; nb < 4; nb++){
      bf16x8_t bfr = *(const bf16x8_t*)(wt + (cofs + nb * 16 + lm) * 128 + ks * 32 + lq * 8);
      acc[nb] = __builtin_amdgcn_mfma_f32_16x16x32_bf16(a, bfr, acc[nb], 0, 0, 0);
    }
  }
}

// coalesced lgsa tile stage: 32 rows x 128 u32 -> LDS (pad 132), 4 uint4/thread
__device__ __forceinline__ void stage_lgt(const u32* __restrict__ lgsa_blk,
    u32* __restrict__ lgt, int tid){
  const uint4* src = (const uint4*)lgsa_blk;
  #pragma unroll
  for (int j = 0; j < 4; j++){
    int idx = tid + j * 256;            // 0..1023 uint4
    int row = idx >> 5, colq = idx & 31;
    uint4 v = src[idx];
    *(uint4*)&lgt[row * 132 + colq * 4] = v;
  }
}

// phase 2: states tile (LDS, A-layout) -> gat {EL|S} u32 stores + ea fp16 into
// LDS tile eat (coalesced global writeback by caller).
__device__ __forceinline__ void phase2_awlaw4(const u16* __restrict__ ldstile,
    const u16* __restrict__ Wt, const float* __restrict__ biasf,
    int lm, int lq, int cofs, int r0, _Float16* __restrict__ eat,
    u32* __restrict__ ghw){
  const u16* Wta  = Wt + 16384;
  const u16* Wtla = Wt + 32768;
  const u16* ldsrow = ldstile + lm * 136 + lq * 8;
  f32x4_t accA[4], accL[4];
  #pragma unroll
  for (int i = 0; i < 4; i++){ accA[i] = (f32x4_t){0.f,0.f,0.f,0.f}; accL[i] = (f32x4_t){0.f,0.f,0.f,0.f}; }
  #pragma unroll
  for (int ks = 0; ks < 4; ks++){
    bf16x8_t a = *(const bf16x8_t*)(ldsrow + ks * 32);
    #pragma unroll
    for (int nb = 0; nb < 4; nb++){
      bf16x8_t ba = *(const bf16x8_t*)(Wta  + (cofs + nb * 16 + lm) * 128 + ks * 32 + lq * 8);
      bf16x8_t bl = *(const bf16x8_t*)(Wtla + (cofs + nb * 16 + lm) * 128 + ks * 32 + lq * 8);
      accA[nb] = __builtin_amdgcn_mfma_f32_16x16x32_bf16(a, ba, accA[nb], 0, 0, 0);
      accL[nb] = __builtin_amdgcn_mfma_f32_16x16x32_bf16(a, bl, accL[nb], 0, 0, 0);
    }
  }
  #pragma unroll
  for (int nb = 0; nb < 4; nb++){
    int col = cofs + nb * 16 + lm;
    float bb = biasf[128 + col];
    #pragma unroll
    for (int i = 0; i < 4; i++){
      int row = r0 + lq * 4 + i;
      float ea = fminf(__expf(accA[nb][i]), 60000.0f);   // fp16-safe; exact in ea>>1 limit
      eat[(lq * 4 + i) * 128 + col] = (_Float16)ea;
      u16 el = f2bf(__expf(accL[nb][i] + bb));
      u16 s  = ldstile[(lq * 4 + i) * 136 + col];
      ghw[(size_t)row * 64 + (col & 63)] = (u32)el | ((u32)s << 16);
    }
  }
}

// coalesced eah writeback: 2 tiles x 16 rows x 128 fp16 = 8KB, 16B/thread x2.
__device__ __forceinline__ void eah_writeback(const _Float16* __restrict__ eat,
    _Float16* __restrict__ eah, int blk_r0, int tid){
  const uint4* src = (const uint4*)eat;
  uint4* dst = (uint4*)(eah + (size_t)blk_r0 * 128);
  dst[tid]       = src[tid];
  dst[tid + 256] = src[tid + 256];
}

// init: states = tanh(obj@Wo + b) from raw objects; then eah/EL/S.
__global__ void __launch_bounds__(256) fused_init(const void* __restrict__ obj_raw,
    const int* __restrict__ flag, const u16* __restrict__ Wt,
    const float* __restrict__ biasf, _Float16* __restrict__ eah,
    u32* __restrict__ gat0, u32* __restrict__ gat1){
  __shared__ u16 lds[2][16 * 136];
  __shared__ _Float16 eat[2][16 * 128];
  const int lane = threadIdx.x & 63, wave = threadIdx.x >> 6;
  const int t = wave >> 1, ch = wave & 1, cofs = ch * 64;
  const int r0 = blockIdx.x * 32 + t * 16;
  const int lm = lane & 15, lq = lane >> 4;
  f32x4_t acc[4];
  #pragma unroll
  for (int i = 0; i < 4; i++) acc[i] = (f32x4_t){0.f, 0.f, 0.f, 0.f};
  if (*flag){
    const float* arow = (const float*)obj_raw + (size_t)(r0 + lm) * 128 + lq * 8;
    #pragma unroll
    for (int ks = 0; ks < 4; ks++){
      float4 fa = *(const float4*)(arow + ks * 32);
      float4 fb = *(const float4*)(arow + ks * 32 + 4);
      bf16x8_t a;
      a[0] = (short)f2bf(fa.x); a[1] = (short)f2bf(fa.y);
      a[2] = (short)f2bf(fa.z); a[3] = (short)f2bf(fa.w);
      a[4] = (short)f2bf(fb.x); a[5] = (short)f2bf(fb.y);
      a[6] = (short)f2bf(fb.z); a[7] = (short)f2bf(fb.w);
      #pragma unroll
      for (int nb = 0; nb < 4; nb++){
        bf16x8_t bfr = *(const bf16x8_t*)(Wt + (cofs + nb * 16 + lm) * 128 + ks * 32 + lq * 8);
        acc[nb] = __builtin_amdgcn_mfma_f32_16x16x32_bf16(a, bfr, acc[nb], 0, 0, 0);
      }
    }
  } else {
    gemm_tile4((const u16*)obj_raw + (size_t)(r0 + lm) * 128 + lq * 8, Wt, lm, lq, cofs, acc);
  }
  #pragma unroll
  for (int nb = 0; nb < 4; nb++){
    int col = cofs + nb * 16 + lm;
    float bb = biasf[col];
    #pragma unroll
    for (int i = 0; i < 4; i++)
      lds[t][(lq * 4 + i) * 136 + col] = f2bf(fast_tanh(acc[nb][i] + bb));
  }
  __syncthreads();
  phase2_awlaw4(&lds[t][0], Wt, biasf, lm, lq, cofs, r0, &eat[t][0], ch ? gat1 : gat0);
  __syncthreads();
  eah_writeback(&eat[0][0], eah, blockIdx.x * 32, threadIdx.x);
}

// mid: states = tanh(sa + lg@Wl + b); then eah/EL/S for next iter.
__global__ void __launch_bounds__(256) fused_mid(const u32* __restrict__ lgsa,
    const u16* __restrict__ Wt, const float* __restrict__ biasf,
    _Float16* __restrict__ eah, u32* __restrict__ gat0, u32* __restrict__ gat1){
  __shared__ u32 lgt[32 * 132];
  __shared__ u16 lds[2][16 * 136];
  __shared__ _Float16 eat[2][16 * 128];
  const int lane = threadIdx.x & 63, wave = threadIdx.x >> 6;
  const int t = wave >> 1, ch = wave & 1, cofs = ch * 64;
  const int r0 = blockIdx.x * 32 + t * 16;
  const int lm = lane & 15, lq = lane >> 4;
  stage_lgt(lgsa + (size_t)blockIdx.x * 32 * 128, lgt, threadIdx.x);
  __syncthreads();
  f32x4_t acc[4];
  #pragma unroll
  for (int i = 0; i < 4; i++) acc[i] = (f32x4_t){0.f, 0.f, 0.f, 0.f};
  gemm_tile4_lds(&lgt[(t * 16 + lm) * 132], Wt + 49152, lm, lq, cofs, acc);
  #pragma unroll
  for (int nb = 0; nb < 4; nb++){
    int col = cofs + nb * 16 + lm;
    float bb = biasf[col];
    #pragma unroll
    for (int i = 0; i < 4; i++){
      u32 v = lgt[(t * 16 + lq * 4 + i) * 132 + col];
      u16 hb = (u16)(v >> 16);
      float sa = (float)(*(const _Float16*)&hb);
      lds[t][(lq * 4 + i) * 136 + col] = f2bf(fast_tanh(sa + acc[nb][i] + bb));
    }
  }
  __syncthreads();
  phase2_awlaw4(&lds[t][0], Wt, biasf, lm, lq, cofs, r0, &eat[t][0], ch ? gat1 : gat0);
  __syncthreads();
  eah_writeback(&eat[0][0], eah, blockIdx.x * 32, threadIdx.x);
}

// final: out = tanh(sa + lg@Wl + b), fp32 or bf16 per flag.
__global__ void __launch_bounds__(256) final_out(const u32* __restrict__ lgsa,
    const u16* __restrict__ Wt, const float* __restrict__ biasf,
    const int* __restrict__ flag, void* __restrict__ outp){
  __shared__ u32 lgt[32 * 132];
  const int lane = threadIdx.x & 63, wave = threadIdx.x >> 6;
  const int t = wave >> 1, ch = wave & 1, cofs = ch * 64;
  const int r0 = blockIdx.x * 32 + t * 16;
  const int lm = lane & 15, lq = lane >> 4;
  bool f32out = (*flag != 0);
  stage_lgt(lgsa + (size_t)blockIdx.x * 32 * 128, lgt, threadIdx.x);
  __syncthreads();
  f32x4_t acc[4];
  #pragma unroll
  for (int i = 0; i < 4; i++) acc[i] = (f32x4_t){0.f, 0.f, 0.f, 0.f};
  gemm_tile4_lds(&lgt[(t * 16 + lm) * 132], Wt + 49152, lm, lq, cofs, acc);
  #pragma unroll
  for (int nb = 0; nb < 4; nb++){
    int col = cofs + nb * 16 + lm;
    float bb = biasf[col];
    #pragma unroll
    for (int i = 0; i < 4; i++){
      int row = r0 + lq * 4 + i;
      u32 vv = lgt[(t * 16 + lq * 4 + i) * 132 + col];
      u16 hb = (u16)(vv >> 16);
      float sa = (float)(*(const _Float16*)&hb);
      float v = fast_tanh(sa + acc[nb][i] + bb);
      if (f32out) ((float*)outp)[(size_t)row * 128 + col] = v;
      else        ((u16*)  outp)[(size_t)row * 128 + col] = f2bf(v);
    }
  }
}

// ---------------- edge gather: half-channel split, 1 wave/node ----------------
__device__ __forceinline__ void acc_e(u32 g, float& s1, float& s2){
  float el = __uint_as_float(g << 16);
  float sv = __uint_as_float(g & 0xffff0000u);
  s1 += el;
  s2 = fmaf(el, sv, s2);
}

__global__ void __launch_bounds__(256) edge_kernel(const _Float16* __restrict__ eah,
    const u32* __restrict__ gat0, const u32* __restrict__ gat1,
    const int* __restrict__ row_start, const u16* __restrict__ edge_dst,
    u32* __restrict__ lgsa){
  int blk = blockIdx.x;
  int xcd = blk & 7;
  int b = xcd >> 1, h = xcd & 1;
  int i = blk >> 3;                          // 0..2499
  int n = i * 4 + (int)(threadIdx.x >> 6);
  int node = b * NNODE + n;
  int c = threadIdx.x & 63;
  const u32* gh = (h ? gat1 : gat0) + (size_t)b * NNODE * 64;
  int e0 = __builtin_amdgcn_readfirstlane(row_start[b * (NNODE + 1) + n]);
  int e1 = __builtin_amdgcn_readfirstlane(row_start[b * (NNODE + 1) + n + 1]);
  const u16* ed = edge_dst + (size_t)b * TWOE;

  float ea = (float)eah[(size_t)node * 128 + h * 64 + c];
  float s1 = 0.f, s2 = 0.f, t1 = 0.f, t2 = 0.f;
  int e = e0;
  for (; e + 16 <= e1; e += 16){
    u32 d[16];
    #pragma unroll
    for (int k = 0; k < 16; k++) d[k] = ed[e + k];
    u32 g[16];
    #pragma unroll
    for (int k = 0; k < 16; k++) g[k] = gh[(size_t)d[k] * 64 + c];
    #pragma unroll
    for (int k = 0; k < 16; k += 2){ acc_e(g[k], s1, s2); acc_e(g[k + 1], t1, t2); }
  }
  for (; e + 4 <= e1; e += 4){
    u32 d0 = ed[e], d1 = ed[e+1], d2 = ed[e+2], d3 = ed[e+3];
    u32 g0 = gh[(size_t)d0 * 64 + c];
    u32 g1 = gh[(size_t)d1 * 64 + c];
    u32 g2 = gh[(size_t)d2 * 64 + c];
    u32 g3 = gh[(size_t)d3 * 64 + c];
    acc_e(g0, s1, s2); acc_e(g1, t1, t2);
    acc_e(g2, s1, s2); acc_e(g3, t1, t2);
  }
  for (; e < e1; e++){
    u32 gg = gh[(size_t)ed[e] * 64 + c];
    acc_e(gg, s1, s2);
  }
  s1 += t1; s2 += t2;
  float inv = __builtin_amdgcn_rcpf(fmaf(ea, s1, 1.0f));
  float lg = ea * s2 * inv;
  u32 self = gh[(size_t)n * 64 + c];
  float s_self = __uint_as_float(self & 0xffff0000u);
  _Float16 hs = (_Float16)(s_self * inv);
  u32 pk = (u32)f2bf(lg) | ((u32)(*(const u16*)&hs) << 16);
  lgsa[(size_t)node * 128 + h * 64 + c] = pk;
}

// ---------------- host launcher ----------------------------------------------
extern "C" void kernel_launch(void* const* d_in, const int* in_sizes, int n_in,
                              void* d_out, int out_size, void* d_ws, size_t ws_size,
                              hipStream_t stream){
  (void)in_sizes; (void)n_in; (void)ws_size; (void)out_size;
  const void* objects = d_in[0];
  const void* Wo      = d_in[1];
  const void* Wa      = d_in[2];
  const void* Wla     = d_in[3];
  const void* attn_b  = d_in[4];
  const void* Wl      = d_in[5];
  const void* state_b = d_in[6];
  const int*  conn    = (const int*)d_in[7];

  char* base = (char*)d_ws;
  size_t off = 0;
  auto alloc = [&](size_t bytes) -> char* {
    char* p = base + off;
    off = (off + bytes + 255) & ~(size_t)255;
    return p;
  };
  int*      flag      = (int*)     alloc(256);
  u16*      Wt        = (u16*)     alloc((size_t)4 * 16384 * 2);
  float*    biasf     = (float*)   alloc(256 * 4);
  _Float16* eah       = (_Float16*)alloc((size_t)MROWS * 128 * 2);  // exp(aW) fp16
  u32*      gat0      = (u32*)     alloc((size_t)MROWS * 64 * 4);   // ch 0-63 {EL|S}
  u32*      gat1      = (u32*)     alloc((size_t)MROWS * 64 * 4);   // ch 64-127
  u32*      lgsa      = (u32*)     alloc((size_t)MROWS * 128 * 4);  // {lg bf16 | sa fp16}
  u16*      partial   = (u16*)     alloc((size_t)BATCH * NCHUNK * PADN * 2);
  int*      row_start = (int*)     alloc((size_t)BATCH * (NNODE + 1) * 4);
  u16*      edge_dst  = (u16*)     alloc((size_t)BATCH * TWOE * 2);
  int*      bsum      = (int*)     alloc(160 * 4);
  int*      boff      = (int*)     alloc(160 * 4);

  detect_dtype<<<1, 256, 0, stream>>>((const u32*)objects, flag);
  prep_weights<<<257, 256, 0, stream>>>(Wo, Wa, Wla, Wl, attn_b, state_b, flag, Wt, biasf);

  csr_hist<<<256, 256, 0, stream>>>(conn, partial);
  csr_colscan<<<160, 256, 0, stream>>>(partial, row_start, bsum);
  scanB<<<1, 256, 0, stream>>>(bsum, boff, row_start);
  scanC<<<160, 256, 0, stream>>>(row_start, boff);
  csr_fill<<<256, 256, 0, stream>>>(conn, partial, row_start, edge_dst);

  fused_init<<<MROWS / 32, 256, 0, stream>>>(objects, flag, Wt, biasf, eah, gat0, gat1);
  edge_kernel<<<MROWS / 2, 256, 0, stream>>>(eah, gat0, gat1, row_start, edge_dst, lgsa);
  fused_mid<<<MROWS / 32, 256, 0, stream>>>(lgsa, Wt, biasf, eah, gat0, gat1);
  edge_kernel<<<MROWS / 2, 256, 0, stream>>>(eah, gat0, gat1, row_start, edge_dst, lgsa);
  fused_mid<<<MROWS / 32, 256, 0, stream>>>(lgsa, Wt, biasf, eah, gat0, gat1);
  edge_kernel<<<MROWS / 2, 256, 0, stream>>>(eah, gat0, gat1, row_start, edge_dst, lgsa);
  final_out<<<MROWS / 32, 256, 0, stream>>>(lgsa, Wt, biasf, flag, d_out);
}